// Round 3
// baseline (822.064 us; speedup 1.0000x reference)
//
#include <hip/hip_runtime.h>

#define B_ 16
#define C_ 512
#define K_ 128
#define N_ 4096   // H*W = 64*64
#define NKEEP 51  // int(0.1 * 512)

typedef short s8v __attribute__((ext_vector_type(8)));   // 8 bf16 (4 VGPRs)
typedef float f4v __attribute__((ext_vector_type(4)));   // 4 fp32 acc

__device__ __forceinline__ unsigned short f2bf(float f) {
    union { float f; unsigned u; } v; v.f = f;
    unsigned r = (v.u + 0x7FFFu + ((v.u >> 16) & 1u)) >> 16;  // RNE
    return (unsigned short)r;
}

// ---------------------------------------------------------------------------
// K1: depthwise 3x3 conv for k (fp32, [B][K][N]) and v (bf16, transposed to
// vt [B][N][K] via LDS). Block: (b, 32-pixel half-row); 256 thr = 8 kq x 32 px.
__global__ __launch_bounds__(256) void conv_kv_kernel(const float* __restrict__ xkv,
                               const float* __restrict__ wk, const float* __restrict__ bk,
                               const float* __restrict__ wv, const float* __restrict__ bv,
                               float* __restrict__ kbuf, unsigned short* __restrict__ vt) {
    __shared__ unsigned short vs[32][136];   // [px][k], pad 128->136 (16B-aligned rows)
    int blk = blockIdx.x;        // B x 128
    int t  = blk & 127;
    int b  = blk >> 7;
    int n0 = t * 32;
    int y = n0 >> 6, x0 = n0 & 63;
    int tid = threadIdx.x;
    int kq = tid >> 5, px = tid & 31;
    int x = x0 + px;

#pragma unroll 4
    for (int i = 0; i < 16; ++i) {
        int k = kq * 16 + i;
        const float* wkp = wk + k * 9;
        const float* wvp = wv + k * 9;
        const float* xp  = xkv + ((size_t)(b * K_ + k)) * N_;
        float ak = bk[k], av = bv[k];
#pragma unroll
        for (int dy = 0; dy < 3; ++dy) {
            int yy = y + dy - 1;
            if (yy < 0 || yy > 63) continue;
            const float* row = xp + yy * 64;
#pragma unroll
            for (int dx = 0; dx < 3; ++dx) {
                int xx = x + dx - 1;
                if (xx < 0 || xx > 63) continue;
                float val = row[xx];
                ak += val * wkp[dy * 3 + dx];
                av += val * wvp[dy * 3 + dx];
            }
        }
        kbuf[((size_t)(b * K_ + k)) * N_ + n0 + px] = ak;
        vs[px][k] = f2bf(av);
    }
    __syncthreads();
    // transposed write-out: 32 n-rows x 8 k-groups of 16
    {
        int n = tid >> 3, kg = (tid & 7) * 16;
        s8v w0, w1;
#pragma unroll
        for (int i = 0; i < 8; ++i) {
            w0[i] = (short)vs[n][kg + i];
            w1[i] = (short)vs[n][kg + 8 + i];
        }
        unsigned short* dst = vt + ((size_t)(b * N_ + n0 + n)) * K_ + kg;
        *(s8v*)dst = w0;
        *(s8v*)(dst + 8) = w1;
    }
}

// ---------------------------------------------------------------------------
// K2: depthwise 3x3 conv for q from x_q -> fp32 qb [B][C][N] (in d_out scratch)
__global__ void conv_q_kernel(const float* __restrict__ xq,
                              const float* __restrict__ wq, const float* __restrict__ bq,
                              float* __restrict__ qb) {
    int idx = blockIdx.x * 256 + threadIdx.x;   // over B*C*N
    int x = idx & 63;
    int y = (idx >> 6) & 63;
    int c = (idx >> 12) & 511;
    const float* wp = wq + c * 9;
    const float* xp = xq + ((size_t)(idx >> 12)) * N_;
    float a = bq[c];
#pragma unroll
    for (int dy = 0; dy < 3; ++dy) {
        int yy = y + dy - 1;
        if (yy < 0 || yy > 63) continue;
#pragma unroll
        for (int dx = 0; dx < 3; ++dx) {
            int xx = x + dx - 1;
            if (xx < 0 || xx > 63) continue;
            a += xp[yy * 64 + xx] * wp[dy * 3 + dx];
        }
    }
    qb[idx] = a;
}

// ---------------------------------------------------------------------------
// K3: zero the logits accumulator (aw region of d_out) - poisoned each launch.
__global__ void zero_aw_kernel(float4* __restrict__ aw4) {
    aw4[blockIdx.x * 256 + threadIdx.x] = (float4){0.f, 0.f, 0.f, 0.f};
}

// ---------------------------------------------------------------------------
// K4: fp32 QK^T: logits[b][c][k] += dot(q[c,:], k[k,:]) * scale over n-chunk.
// Grid = B x 8 ctiles(64) x 4 splits(1024). 256 thr; thread tile 4c x 8k.
// k-tile LDS uses a +4-shift swizzle (col = k + (k>>5)*4) -> 2-way banking.
__global__ __launch_bounds__(256) void qk_fp32_kernel(const float* __restrict__ qb,
                                                      const float* __restrict__ kb,
                                                      float* __restrict__ aw) {
    __shared__ float qs[32][68];    // [px][c] pad 64->68
    __shared__ float ks[32][140];   // [px][swizzled k] (max col 139)
    int blk = blockIdx.x;
    int s  = blk & 3;
    int ct = (blk >> 2) & 7;
    int b  = blk >> 5;
    int c0 = ct * 64;
    int tid = threadIdx.x;
    int tc = tid >> 4, tk = tid & 15;
    int koff = tk * 8 + (tk >> 2) * 4;          // swizzled base of this thread's 8 k
    // staging roles
    int cq = tid & 63, gq = tid >> 6;           // q: channel, pixel-group
    int kl = tid >> 1, hk = tid & 1;            // k: k-row, half
    int kphys = kl + ((kl >> 5) << 2);          // swizzled column for k-row kl

    const float* qbase = qb + ((size_t)(b * C_ + c0 + cq)) * N_ + s * 1024;
    const float* kbase = kb + ((size_t)(b * K_ + kl)) * N_ + s * 1024;

    float acc[4][8];
#pragma unroll
    for (int i = 0; i < 4; ++i)
#pragma unroll
        for (int j = 0; j < 8; ++j) acc[i][j] = 0.f;

    for (int nb = 0; nb < 1024; nb += 32) {
        __syncthreads();
        // stage q: 64c x 32px, 2 float4 per thread (scatter transposed)
#pragma unroll
        for (int j = 0; j < 2; ++j) {
            int px0 = (gq * 2 + j) * 4;
            float4 v = *(const float4*)(qbase + nb + px0);
            qs[px0][cq] = v.x; qs[px0 + 1][cq] = v.y;
            qs[px0 + 2][cq] = v.z; qs[px0 + 3][cq] = v.w;
        }
        // stage k: 128k x 32px, 4 float4 per thread (scatter transposed+swizzled)
#pragma unroll
        for (int j = 0; j < 4; ++j) {
            int px0 = hk * 16 + j * 4;
            float4 v = *(const float4*)(kbase + nb + px0);
            ks[px0][kphys] = v.x; ks[px0 + 1][kphys] = v.y;
            ks[px0 + 2][kphys] = v.z; ks[px0 + 3][kphys] = v.w;
        }
        __syncthreads();
#pragma unroll 4
        for (int px = 0; px < 32; ++px) {
            float4 qv = *(const float4*)&qs[px][tc * 4];
            float4 k0 = *(const float4*)&ks[px][koff];
            float4 k1 = *(const float4*)&ks[px][koff + 4];
            float qa[4] = {qv.x, qv.y, qv.z, qv.w};
            float ka[8] = {k0.x, k0.y, k0.z, k0.w, k1.x, k1.y, k1.z, k1.w};
#pragma unroll
            for (int i = 0; i < 4; ++i)
#pragma unroll
                for (int j = 0; j < 8; ++j) acc[i][j] += qa[i] * ka[j];
        }
    }
    const float scale = 0.08838834764831845f; // 1/sqrt(128)
#pragma unroll
    for (int i = 0; i < 4; ++i) {
        float* dst = aw + ((size_t)(b * C_ + c0 + tc * 4 + i)) * K_ + tk * 8;
#pragma unroll
        for (int j = 0; j < 8; ++j)
            atomicAdd(&dst[j], acc[i][j] * scale);
    }
}

// ---------------------------------------------------------------------------
// K5: softmax over k (128) per (b,c) row, in place. One wave per row.
__global__ void softmax_kernel(float* __restrict__ aw) {
    int tid  = threadIdx.x;
    int wave = tid >> 6;
    int lane = tid & 63;
    int row  = blockIdx.x * 4 + wave;   // over B*C
    float* p = aw + (size_t)row * K_;
    float v0 = p[lane], v1 = p[lane + 64];
    float m = fmaxf(v0, v1);
#pragma unroll
    for (int s = 32; s >= 1; s >>= 1) m = fmaxf(m, __shfl_xor(m, s, 64));
    float e0 = __expf(v0 - m), e1 = __expf(v1 - m);
    float sum = e0 + e1;
#pragma unroll
    for (int t = 32; t >= 1; t >>= 1) sum += __shfl_xor(sum, t, 64);
    float inv = 1.0f / sum;
    p[lane] = e0 * inv;
    p[lane + 64] = e1 * inv;
}

// ---------------------------------------------------------------------------
// K6: per (b,k) column over c (512): exact 51st-largest via bit binary search,
// zero the rest in aw (fp32) and emit bf16 awb [B][C][K].
__global__ void topk_mask_kernel(float* __restrict__ aw, unsigned short* __restrict__ awb) {
    int tid  = threadIdx.x;
    int wave = tid >> 6, lane = tid & 63;
    int col  = blockIdx.x * 4 + wave;   // over B*K
    int b = col >> 7, k = col & 127;
    float* base = aw + (size_t)(b * C_) * K_ + k;
    unsigned short* bb = awb + (size_t)(b * C_) * K_ + k;
    unsigned u[8];
#pragma unroll
    for (int j = 0; j < 8; ++j)
        u[j] = __float_as_uint(base[(size_t)(j * 64 + lane) * K_]);
    unsigned T = 0;
#pragma unroll
    for (int bit = 31; bit >= 0; --bit) {
        unsigned cand = T | (1u << bit);
        int cnt = 0;
#pragma unroll
        for (int j = 0; j < 8; ++j) cnt += (u[j] >= cand) ? 1 : 0;
#pragma unroll
        for (int s = 32; s >= 1; s >>= 1) cnt += __shfl_xor(cnt, s, 64);
        if (cnt >= NKEEP) T = cand;
    }
#pragma unroll
    for (int j = 0; j < 8; ++j) {
        unsigned kept = (u[j] >= T) ? u[j] : 0u;
        if (u[j] < T) base[(size_t)(j * 64 + lane) * K_] = 0.0f;
        bb[(size_t)(j * 64 + lane) * K_] = f2bf(__uint_as_float(kept));
    }
}

// ---------------------------------------------------------------------------
// K7: attn_out = awb @ v (via vt), + x_q residual. bf16 MFMA, LDS-free.
// grid = B x 8 ctiles x 64 ntiles; wave: 16c x 64n, full K=128 contraction.
__global__ __launch_bounds__(256) void av_kernel(const unsigned short* __restrict__ awb,
                                                 const unsigned short* __restrict__ vt,
                                                 const float* __restrict__ xq,
                                                 float* __restrict__ out) {
    int blk = blockIdx.x;
    int nt = blk & 63;
    int ct = (blk >> 6) & 7;
    int b  = blk >> 9;
    int n0 = nt * 64, c0 = ct * 64;
    int tid = threadIdx.x;
    int w = tid >> 6, l = tid & 63;
    int lr = l & 15, lq = l >> 4;
    int c_base = c0 + w * 16;

    const unsigned short* arow = awb + (size_t)(b * C_ + c_base + lr) * K_ + lq * 8;
    const unsigned short* vbase = vt + (size_t)(b * N_ + n0) * K_ + lq * 8;

    f4v acc[4];
#pragma unroll
    for (int i = 0; i < 4; ++i) acc[i] = (f4v){0.f, 0.f, 0.f, 0.f};

#pragma unroll
    for (int ks = 0; ks < 4; ++ks) {
        s8v a = *(const s8v*)(arow + ks * 32);
#pragma unroll
        for (int nsub = 0; nsub < 4; ++nsub) {
            s8v bf = *(const s8v*)(vbase + (size_t)(nsub * 16 + lr) * K_ + ks * 32);
            acc[nsub] = __builtin_amdgcn_mfma_f32_16x16x32_bf16(a, bf, acc[nsub], 0, 0, 0);
        }
    }
    // epilogue: out = x_q + acc ; D layout col(n)=lane&15, row(c)=quad*4+reg
#pragma unroll
    for (int nsub = 0; nsub < 4; ++nsub) {
#pragma unroll
        for (int r = 0; r < 4; ++r) {
            int c = c_base + lq * 4 + r;
            size_t idx = (size_t)(b * C_ + c) * N_ + n0 + nsub * 16 + lr;
            out[idx] = xq[idx] + acc[nsub][r];
        }
    }
}

// ---------------------------------------------------------------------------
extern "C" void kernel_launch(void* const* d_in, const int* in_sizes, int n_in,
                              void* d_out, int out_size, void* d_ws, size_t ws_size,
                              hipStream_t stream) {
    const float* xq  = (const float*)d_in[0];
    const float* xkv = (const float*)d_in[1];
    const float* wq  = (const float*)d_in[2];
    const float* bq  = (const float*)d_in[3];
    const float* wk  = (const float*)d_in[4];
    const float* bk  = (const float*)d_in[5];
    const float* wv  = (const float*)d_in[6];
    const float* bv  = (const float*)d_in[7];

    float* out0 = (float*)d_out;                        // [16,512,64,64] fp32
    float* aw   = out0 + (size_t)B_ * C_ * N_;          // [16,512,128] fp32

    // ws: kb fp32 (33.6 MB) + vt bf16 (16.8 MB) + awb bf16 (2.1 MB) = 52.4 MB
    float* kb = (float*)d_ws;
    unsigned short* vt  = (unsigned short*)(kb + (size_t)B_ * K_ * N_);
    unsigned short* awb = vt + (size_t)B_ * K_ * N_;

    // d_out.out0 region doubles as fp32 qb scratch until av overwrites it
    float* qb = out0;

    conv_kv_kernel<<<B_ * 128, 256, 0, stream>>>(xkv, wk, bk, wv, bv, kb, vt);
    conv_q_kernel<<<(B_ * C_ * N_) / 256, 256, 0, stream>>>(xq, wq, bq, qb);
    zero_aw_kernel<<<(B_ * C_ * K_) / 1024, 256, 0, stream>>>((float4*)aw);
    qk_fp32_kernel<<<B_ * 8 * 4, 256, 0, stream>>>(qb, kb, aw);
    softmax_kernel<<<(B_ * C_) / 4, 256, 0, stream>>>(aw);
    topk_mask_kernel<<<(B_ * K_) / 4, 256, 0, stream>>>(aw, awb);
    av_kernel<<<B_ * 8 * 64, 256, 0, stream>>>(awb, vt, xq, out0);
}